// Round 15
// baseline (539.515 us; speedup 1.0000x reference)
//
#include <hip/hip_runtime.h>
#include <hip/hip_bf16.h>
#include <math.h>

// GPT_86715389706669 — hierarchical char/word transformer forward.
// Round 15: R14 base (528us) + BN=32 GEMM variant for the four N<=512
// 2-blocks/CU GEMMs (cattn_proj, wattn_proj, mlp_proj, U@Wv EPI4):
// grid 512 -> 1024 blocks (4/CU). Same empirical lever as R3/R9 mlp_fc.

namespace {

constexpr int Bn = 8, Wn = 512, CB = 24, Cd = 512, Hn = 8, Lln = 2, Vn = 256, HDn = 64;
constexpr int BW = Bn * Wn;       // 4096
constexpr int C3 = 3 * Cd;        // 1536
constexpr int FF = 4 * Cd;        // 2048
constexpr int NROW = BW * CB;     // 98304 char rows (strided layout)

typedef unsigned short u16;
typedef short short8 __attribute__((ext_vector_type(8)));
typedef float f32x4 __attribute__((ext_vector_type(4)));
typedef __attribute__((address_space(1))) void gvoid_t;
typedef __attribute__((address_space(3))) void lvoid_t;

__device__ __forceinline__ u16 f2bu(float f) {
  __hip_bfloat16 h = __float2bfloat16(f);   // RTNE
  return __builtin_bit_cast(u16, h);
}
__device__ __forceinline__ float bu2f(u16 u) {
  return __bfloat162float(__builtin_bit_cast(__hip_bfloat16, u));
}
__device__ __forceinline__ float geluf(float x) {
  return 0.5f * x * (1.0f + erff(x * 0.7071067811865475f));
}
__device__ __forceinline__ void gl16(const void* g, void* l) {
  __builtin_amdgcn_global_load_lds((gvoid_t*)g, (lvoid_t*)l, 16, 0, 0);
}

// ---------------- consolidated weight prep (+ lastix) ----------------
__device__ __forceinline__ void f2b8(const float* __restrict__ s, u16* __restrict__ d) {
  float4 a = *(const float4*)s;
  float4 b = *(const float4*)(s + 4);
  union { uint4 u; u16 h[8]; } pk;
  pk.h[0] = f2bu(a.x); pk.h[1] = f2bu(a.y); pk.h[2] = f2bu(a.z); pk.h[3] = f2bu(a.w);
  pk.h[4] = f2bu(b.x); pk.h[5] = f2bu(b.y); pk.h[6] = f2bu(b.z); pk.h[7] = f2bu(b.w);
  *(uint4*)d = pk.u;
}

__device__ __forceinline__ void wT_tile(const float* __restrict__ src, u16* __restrict__ dst,
                                        int K, int N, int n0, int k0,
                                        u16 T[64][72], int tid) {
  int kl = tid >> 2, nc = (tid & 3) * 16;
  const float* s = src + (long)(k0 + kl) * N + n0 + nc;
#pragma unroll
  for (int u = 0; u < 4; ++u) {
    float4 f = *(const float4*)(s + u * 4);
    T[nc + u * 4 + 0][kl] = f2bu(f.x);
    T[nc + u * 4 + 1][kl] = f2bu(f.y);
    T[nc + u * 4 + 2][kl] = f2bu(f.z);
    T[nc + u * 4 + 3][kl] = f2bu(f.w);
  }
  __syncthreads();
  int nl = tid >> 2, kc = (tid & 3) * 16;
  u16* d = dst + (long)(n0 + nl) * K + k0 + kc;
  *(uint4*)d = *(uint4*)&T[nl][kc];
  *(uint4*)(d + 8) = *(uint4*)&T[nl][kc + 8];
}

// grid = 3072 (projwb) + 768 (wcb) + 32 (lmhT) + 2048 (wT) + 16 (lastix) = 5936
__global__ __launch_bounds__(256) void k_prep(
    const float* __restrict__ proj_w, u16* __restrict__ projwb,
    const float* __restrict__ cattn_w, u16* __restrict__ wcb,
    const float* __restrict__ lm_head, u16* __restrict__ lmhT,
    const float* __restrict__ cattn_proj, const float* __restrict__ wattn_w,
    const float* __restrict__ wattn_proj, const float* __restrict__ mlp_fc,
    const float* __restrict__ mlp_proj, u16* __restrict__ wT,
    const int* __restrict__ amask, int* __restrict__ lastix) {
  __shared__ u16 T[64][72];
  int b = blockIdx.x, tid = threadIdx.x;
  if (b >= 5920) {
    int i = (b - 5920) * 256 + tid;
    if (i < BW) {
      int s = 0;
#pragma unroll
      for (int j = 0; j < CB; ++j) s += amask[i * CB + j];
      lastix[i] = s - 1;
    }
    return;
  }
  if (b < 3072) { long i = ((long)b * 256 + tid) * 8; f2b8(proj_w + i, projwb + i); return; }
  b -= 3072;
  if (b < 768) { long i = ((long)b * 256 + tid) * 8; f2b8(cattn_w + i, wcb + i); return; }
  b -= 768;
  if (b < 32) { wT_tile(lm_head, lmhT, Cd, Vn, (b & 3) * 64, (b >> 2) * 64, T, tid); return; }
  b -= 32;
  int l = b >> 10, r = b & 1023;
  size_t lw = (size_t)(2 * C3 * Cd + 2 * Cd * Cd + 2 * FF * Cd);
  u16* bl = wT + l * lw;
  const float* src; u16* dst; int K, N, nt;
  if (r < 192)      { src = cattn_w + (size_t)l * Cd * C3;    dst = bl;                              K = Cd; N = C3; nt = 24; }
  else if (r < 256) { src = cattn_proj + (size_t)l * Cd * Cd; dst = bl + C3 * Cd;                    K = Cd; N = Cd; nt = 8;  r -= 192; }
  else if (r < 448) { src = wattn_w + (size_t)l * Cd * C3;    dst = bl + C3 * Cd + Cd * Cd;          K = Cd; N = C3; nt = 24; r -= 256; }
  else if (r < 512) { src = wattn_proj + (size_t)l * Cd * Cd; dst = bl + 2 * C3 * Cd + Cd * Cd;      K = Cd; N = Cd; nt = 8;  r -= 448; }
  else if (r < 768) { src = mlp_fc + (size_t)l * Cd * FF;     dst = bl + 2 * C3 * Cd + 2 * Cd * Cd;  K = Cd; N = FF; nt = 32; r -= 512; }
  else              { src = mlp_proj + (size_t)l * FF * Cd;   dst = bl + 2 * C3 * Cd + 2 * Cd * Cd + FF * Cd; K = FF; N = Cd; nt = 8; r -= 768; }
  wT_tile(src, dst, K, N, (r % nt) * 64, (r / nt) * 64, T, tid);
}

// ---------------- fused embed + LN -> ctx (+ last row to qin) ----------------
__global__ __launch_bounds__(64) void k_embed_ln(
    const int* __restrict__ x, const float* __restrict__ cte, const float* __restrict__ cpe,
    const float* __restrict__ g, const float* __restrict__ b,
    const int* __restrict__ lastix, u16* __restrict__ ctx, u16* __restrict__ qin) {
  int r = blockIdx.x;
  int bw = r / CB, ch = r - bw * CB;
  int li = lastix[bw];
  if (ch > li) return;
  int tok = x[r];
  const float* e = cte + (long)tok * Cd;
  const float* pe = cpe + (long)ch * Cd;
  int lane = threadIdx.x;
  float v[8];
  float s = 0.f, sq = 0.f;
#pragma unroll
  for (int u = 0; u < 2; ++u) {
    float4 a = *(const float4*)(e + u * 256 + lane * 4);
    float4 p4 = *(const float4*)(pe + u * 256 + lane * 4);
    v[u * 4 + 0] = a.x + p4.x; v[u * 4 + 1] = a.y + p4.y;
    v[u * 4 + 2] = a.z + p4.z; v[u * 4 + 3] = a.w + p4.w;
  }
#pragma unroll
  for (int u = 0; u < 8; ++u) { s += v[u]; sq += v[u] * v[u]; }
#pragma unroll
  for (int m = 32; m; m >>= 1) { s += __shfl_xor(s, m); sq += __shfl_xor(sq, m); }
  float mean = s * (1.0f / Cd);
  float var = sq * (1.0f / Cd) - mean * mean;
  float rs = rsqrtf(var + 1e-5f);
  u16* o = ctx + (long)r * Cd;
  u16* oq = qin + (long)bw * Cd;
  int isLast = (ch == li);
#pragma unroll
  for (int u = 0; u < 2; ++u) {
    int c0 = u * 256 + lane * 4;
    float4 g4 = *(const float4*)(g + c0);
    float4 b4 = *(const float4*)(b + c0);
    float o0 = (v[u * 4 + 0] - mean) * rs * g4.x + b4.x;
    float o1 = (v[u * 4 + 1] - mean) * rs * g4.y + b4.y;
    float o2 = (v[u * 4 + 2] - mean) * rs * g4.z + b4.z;
    float o3 = (v[u * 4 + 3] - mean) * rs * g4.w + b4.w;
    uint2 w;
    w.x = (unsigned)f2bu(o0) | ((unsigned)f2bu(o1) << 16);
    w.y = (unsigned)f2bu(o2) | ((unsigned)f2bu(o3) << 16);
    *(uint2*)(o + c0) = w;
    if (isLast) *(uint2*)(oq + c0) = w;
  }
}

// ---------------- LayerNorm rows [BW, C], f32 in -> bf16 out ----------------
__global__ __launch_bounds__(64) void k_ln(
    const float* __restrict__ X, u16* __restrict__ Y,
    const float* __restrict__ g, const float* __restrict__ b) {
  long r = blockIdx.x;
  const float* xr = X + r * Cd;
  int lane = threadIdx.x;
  float v[8];
  float s = 0.f, sq = 0.f;
#pragma unroll
  for (int u = 0; u < 2; ++u) {
    float4 a = *(const float4*)(xr + u * 256 + lane * 4);
    v[u * 4 + 0] = a.x; v[u * 4 + 1] = a.y; v[u * 4 + 2] = a.z; v[u * 4 + 3] = a.w;
  }
#pragma unroll
  for (int u = 0; u < 8; ++u) { s += v[u]; sq += v[u] * v[u]; }
#pragma unroll
  for (int m = 32; m; m >>= 1) { s += __shfl_xor(s, m); sq += __shfl_xor(sq, m); }
  float mean = s * (1.0f / Cd);
  float var = sq * (1.0f / Cd) - mean * mean;
  float rs = rsqrtf(var + 1e-5f);
  u16* o = Y + r * Cd;
#pragma unroll
  for (int u = 0; u < 2; ++u) {
    int c0 = u * 256 + lane * 4;
    float4 g4 = *(const float4*)(g + c0);
    float4 b4 = *(const float4*)(b + c0);
    float o0 = (v[u * 4 + 0] - mean) * rs * g4.x + b4.x;
    float o1 = (v[u * 4 + 1] - mean) * rs * g4.y + b4.y;
    float o2 = (v[u * 4 + 2] - mean) * rs * g4.z + b4.z;
    float o3 = (v[u * 4 + 3] - mean) * rs * g4.w + b4.w;
    uint2 w;
    w.x = (unsigned)f2bu(o0) | ((unsigned)f2bu(o1) << 16);
    w.y = (unsigned)f2bu(o2) | ((unsigned)f2bu(o3) << 16);
    *(uint2*)(o + c0) = w;
  }
}

// ---------------- bf16 MFMA GEMM: D = A @ Bt^T ----------------
// BN=32 variant: WN=16, FN=1; B staged by threads < 128 (wave-aligned).
// EPI: 0=store, 1=acc+R, 2=gelu, 3=acc+R dual-store (f32 Cv + bf16 D2),
//      4=acc + PL[gr*8+z2]*VL[gr,2C+z2*64+gc] (+WP)  [char-attn O assembly]
template <int BM, int BN, int EPI, int OUTBF>
__global__ __launch_bounds__(256) void k_mgemm(
    const u16* __restrict__ A, int lda, long sA1, long sA2,
    const u16* __restrict__ Bt, int ldb, long sB1, long sB2,
    void* __restrict__ Cv, int ldc, long sC1, long sC2,
    const float* __restrict__ R, u16* __restrict__ D2,
    const float* __restrict__ PL, const u16* __restrict__ VL,
    const float* __restrict__ WP, int K, int zdiv) {
  constexpr int WM = BM / 2;
  constexpr int WN = BN / 2;
  constexpr int FM = WM / 16, FN = WN / 16;
  __shared__ u16 As[BM * 32];
  __shared__ u16 Bs[BN * 32];
  long m0 = (long)blockIdx.y * BM, n0 = (long)blockIdx.x * BN;
  int z = blockIdx.z;
  int z1 = z / zdiv, z2 = z - z1 * zdiv;
  A += z1 * sA1 + z2 * sA2;
  Bt += z1 * sB1 + z2 * sB2;
  long coff = z1 * sC1 + z2 * sC2;
  int tid = threadIdx.x;
  int wid = tid >> 6, lane = tid & 63;
  int wr = wid >> 1, wc = wid & 1;

  const int srow = tid >> 2, skk = (tid & 3) * 8;
  const u16* Ald[BM / 64];
#pragma unroll
  for (int i = 0; i < BM / 64; ++i) Ald[i] = A + (m0 + srow + i * 64) * (long)lda + skk;
  const u16* Bld[(BN + 63) / 64];
  if constexpr (BN >= 64) {
#pragma unroll
    for (int i = 0; i < BN / 64; ++i) Bld[i] = Bt + (n0 + srow + i * 64) * (long)ldb + skk;
  } else {
    Bld[0] = Bt + (n0 + srow) * (long)ldb + skk;   // valid only for tid<128
  }

  f32x4 acc[FM][FN] = {};
  const int fr = lane & 15, kg = lane >> 4;

  for (int k0 = 0; k0 < K; k0 += 32) {
#pragma unroll
    for (int i = 0; i < BM / 64; ++i) gl16(Ald[i] + k0, &As[(tid + i * 256) * 8]);
    if constexpr (BN >= 64) {
#pragma unroll
      for (int i = 0; i < BN / 64; ++i) gl16(Bld[i] + k0, &Bs[(tid + i * 256) * 8]);
    } else {
      if (tid < 128) gl16(Bld[0] + k0, &Bs[tid * 8]);
    }
    __syncthreads();
    short8 af[FM], bf[FN];
#pragma unroll
    for (int m = 0; m < FM; ++m)
      af[m] = *(const short8*)&As[(wr * WM + m * 16 + fr) * 32 + kg * 8];
#pragma unroll
    for (int n = 0; n < FN; ++n)
      bf[n] = *(const short8*)&Bs[(wc * WN + n * 16 + fr) * 32 + kg * 8];
#pragma unroll
    for (int m = 0; m < FM; ++m)
#pragma unroll
      for (int n = 0; n < FN; ++n)
        acc[m][n] = __builtin_amdgcn_mfma_f32_16x16x32_bf16(af[m], bf[n], acc[m][n], 0, 0, 0);
    __syncthreads();
  }
  // C/D layout: col = lane&15, row = (lane>>4)*4 + q
  int ccol = lane & 15, crow4 = (lane >> 4) * 4;
#pragma unroll
  for (int m = 0; m < FM; ++m)
#pragma unroll
    for (int n = 0; n < FN; ++n)
#pragma unroll
      for (int q = 0; q < 4; ++q) {
        long gr = m0 + wr * WM + m * 16 + crow4 + q;
        long gc = n0 + wc * WN + n * 16 + ccol;
        float v = acc[m][n][q];
        long idx = gr * (long)ldc + gc + coff;
        if (EPI == 1 || EPI == 3) v += R[idx];
        if (EPI == 2) v = geluf(v);
        if (EPI == 4) {
          v += PL[gr * 8 + z2] * bu2f(VL[gr * (long)C3 + 2 * Cd + z2 * 64 + gc]);
          if (WP) v += WP[(long)(gr & (Wn - 1)) * Cd + z2 * 64 + gc];
        }
        if (EPI == 3) {
          ((float*)Cv)[idx] = v;
          D2[idx] = f2bu(v);
        } else if (OUTBF) {
          ((u16*)Cv)[idx] = f2bu(v);
        } else {
          ((float*)Cv)[idx] = v;
        }
      }
}

// ---------------- fused char attention: MFMA scores + MFMA aggregate ----------------
__global__ __launch_bounds__(256) void k_cattn2(
    const u16* __restrict__ ctx, const u16* __restrict__ qtil,
    const u16* __restrict__ qkvc, const int* __restrict__ lastix,
    u16* __restrict__ U, float* __restrict__ plast) {
  constexpr int CS = 520;                  // padded row stride (u16)
  int gw = blockIdx.x;
  int li = lastix[gw];
  __shared__ u16 ctxs[CB - 1][CS];         // rows 0..22 (j = li from qkvc)
  __shared__ float spf[4][Hn][32];         // per-wave score partials
  __shared__ float sp[Hn][CB];
  __shared__ u16 Pb[16][40];               // bf16 P, zero-padded
  int tid = threadIdx.x;
  for (int u = tid; u < li * 64; u += 256) {
    int row = u >> 6, c = (u & 63) * 8;
    *(uint4*)&ctxs[row][c] = *(const uint4*)(ctx + ((long)(gw * CB + row)) * Cd + c);
  }
  for (int u = tid; u < (CB - 1 - li) * 64; u += 256) {   // zero unloaded rows
    int row = li + (u >> 6), c = (u & 63) * 8;
    *(uint4*)&ctxs[row][c] = make_uint4(0, 0, 0, 0);
  }
  __syncthreads();
  int w = tid >> 6, lane = tid & 63;
  int fr = lane & 15, kg = lane >> 4;
  {
    const u16* qbase = qtil + (long)gw * 4096 + (fr & 7) * 512 + w * 128 + kg * 8;
    int r0 = fr;
    int r1 = 16 + fr; if (r1 > CB - 2) r1 = CB - 2;
    f32x4 acc0 = {}, acc1 = {};
#pragma unroll
    for (int kk = 0; kk < 4; ++kk) {
      short8 af = *(const short8*)(qbase + kk * 32);
      short8 b0 = *(const short8*)&ctxs[r0][w * 128 + kk * 32 + kg * 8];
      short8 b1 = *(const short8*)&ctxs[r1][w * 128 + kk * 32 + kg * 8];
      acc0 = __builtin_amdgcn_mfma_f32_16x16x32_bf16(af, b0, acc0, 0, 0, 0);
      acc1 = __builtin_amdgcn_mfma_f32_16x16x32_bf16(af, b1, acc1, 0, 0, 0);
    }
    if (lane < 32) {
      int jj = lane & 15;
#pragma unroll
      for (int q = 0; q < 4; ++q) {
        int h = (lane >> 4) * 4 + q;
        spf[w][h][jj] = acc0[q];
        spf[w][h][16 + jj] = acc1[q];
      }
    }
  }
  __syncthreads();
  {
    int h = tid >> 5, j = tid & 31;
    if (j < CB)
      sp[h][j] = (spf[0][h][j] + spf[1][h][j] + spf[2][h][j] + spf[3][h][j]) * 0.125f;
  }
  for (int u = tid; u < 16 * 40; u += 256) ((u16*)Pb)[u] = 0;
  __syncthreads();
  if (tid < 8) {   // s_{h,li} = q_h . k_h (last row)
    const u16* qq = qkvc + (long)gw * C3 + tid * 64;
    const u16* kk = qq + Cd;
    float s = 0.f;
#pragma unroll
    for (int u = 0; u < 64; ++u) s += bu2f(qq[u]) * bu2f(kk[u]);
    sp[tid][li] = s * 0.125f;
  }
  __syncthreads();
  if (tid < 8) {
    float m = -3.4e38f;
    for (int jj = 0; jj <= li; ++jj) m = fmaxf(m, sp[tid][jj]);
    float s = 0.f;
    for (int jj = 0; jj <= li; ++jj) { float e = expf(sp[tid][jj] - m); sp[tid][jj] = e; s += e; }
    float inv = 1.0f / s;
    for (int jj = 0; jj < li; ++jj) Pb[tid][jj] = f2bu(sp[tid][jj] * inv);
    plast[gw * 8 + tid] = sp[tid][li] * inv;
  }
  __syncthreads();
  // aggregate: per wave 8 n-tiles of 16 d-cols; K = 32 (j, zero-padded)
  {
    short8 pf = *(const short8*)&Pb[fr][kg * 8];
    u16* ub = U + (long)gw * 4096;
#pragma unroll
    for (int t = 0; t < 8; ++t) {
      int n0 = (w * 8 + t) * 16;
      union { short8 v; u16 e[8]; } bf;
#pragma unroll
      for (int u = 0; u < 8; ++u) {
        int k = kg * 8 + u;
        int kc = k < CB - 1 ? k : CB - 2;   // clamp; rows >= li are zero
        bf.e[u] = ctxs[kc][n0 + fr];
      }
      f32x4 a = {};
      a = __builtin_amdgcn_mfma_f32_16x16x32_bf16(pf, bf.v, a, 0, 0, 0);
      if (kg < 2) {
#pragma unroll
        for (int q = 0; q < 4; ++q)
          ub[(kg * 4 + q) * 512 + n0 + fr] = f2bu(a[q]);
      }
    }
  }
}

// ---------------- fused flash word attention (V transposed in-LDS from qkv) ----------------
__global__ __launch_bounds__(256) void k_fattn(
    const u16* __restrict__ qkv, u16* __restrict__ ao) {
  constexpr int ST = 68;                 // LDS row stride (u16)
  __shared__ u16 Ks[64 * ST];
  __shared__ u16 Vs[64 * ST];            // Vs[d][j] (transposed at staging)
  __shared__ u16 Ps[4][16 * ST];
  int qt = blockIdx.x;
  int z  = blockIdx.y;
  int b = z >> 3, h = z & 7;
  int tid = threadIdx.x;
  int w = tid >> 6, lane = tid & 63;
  int fr = lane & 15, kg = lane >> 4;

  short8 qf[2];
  {
    const u16* qp = qkv + ((long)(b * Wn + qt * 64 + w * 16 + fr)) * C3 + h * 64 + kg * 8;
    qf[0] = *(const short8*)qp;
    qf[1] = *(const short8*)(qp + 32);
  }
  f32x4 oacc[4] = {};
  float mrow[4], lrow[4];
#pragma unroll
  for (int q = 0; q < 4; ++q) { mrow[q] = -3.4e38f; lrow[q] = 0.f; }

  for (int kt = 0; kt <= qt; ++kt) {
    __syncthreads();
    {
      int r = tid >> 2, c = (tid & 3) * 16;
      const u16* kp = qkv + ((long)(b * Wn + kt * 64 + r)) * C3 + Cd + h * 64 + c;
      *(uint4*)&Ks[r * ST + c] = *(const uint4*)kp;
      *(uint4*)&Ks[r * ST + c + 8] = *(const uint4*)(kp + 8);
      const u16* vp = kp + Cd;             // qkv V section, same row/cols
      uint4 v0 = *(const uint4*)vp;
      uint4 v1 = *(const uint4*)(vp + 8);
      const u16* e0 = (const u16*)&v0;
      const u16* e1 = (const u16*)&v1;
#pragma unroll
      for (int u = 0; u < 8; ++u) Vs[(c + u) * ST + r] = e0[u];
#pragma unroll
      for (int u = 0; u < 8; ++u) Vs[(c + 8 + u) * ST + r] = e1[u];
    }
    __syncthreads();
    f32x4 s[4];
#pragma unroll
    for (int n = 0; n < 4; ++n) {
      short8 kf0 = *(const short8*)&Ks[(n * 16 + fr) * ST + kg * 8];
      short8 kf1 = *(const short8*)&Ks[(n * 16 + fr) * ST + kg * 8 + 32];
      f32x4 a = {};
      a = __builtin_amdgcn_mfma_f32_16x16x32_bf16(qf[0], kf0, a, 0, 0, 0);
      a = __builtin_amdgcn_mfma_f32_16x16x32_bf16(qf[1], kf1, a, 0, 0, 0);
      s[n] = a;
    }
    int irow0 = qt * 64 + w * 16 + kg * 4;
#pragma unroll
    for (int n = 0; n < 4; ++n) {
      int jcol = kt * 64 + n * 16 + fr;
#pragma unroll
      for (int q = 0; q < 4; ++q) {
        float v = s[n][q] * 0.125f;
        s[n][q] = (jcol > irow0 + q) ? -3.4e38f : v;
      }
    }
    float sf[4];
#pragma unroll
    for (int q = 0; q < 4; ++q) {
      float mm = fmaxf(fmaxf(s[0][q], s[1][q]), fmaxf(s[2][q], s[3][q]));
      mm = fmaxf(mm, __shfl_xor(mm, 1));
      mm = fmaxf(mm, __shfl_xor(mm, 2));
      mm = fmaxf(mm, __shfl_xor(mm, 4));
      mm = fmaxf(mm, __shfl_xor(mm, 8));
      float mnew = fmaxf(mrow[q], mm);
      sf[q] = expf(mrow[q] - mnew);
      mrow[q] = mnew;
    }
    float ls[4] = {0.f, 0.f, 0.f, 0.f};
#pragma unroll
    for (int n = 0; n < 4; ++n) {
#pragma unroll
      for (int q = 0; q < 4; ++q) {
        float p = expf(s[n][q] - mrow[q]);
        u16 pb = f2bu(p);
        ls[q] += bu2f(pb);
        Ps[w][(kg * 4 + q) * ST + n * 16 + fr] = pb;
      }
    }
#pragma unroll
    for (int q = 0; q < 4; ++q) {
      float l = ls[q];
      l += __shfl_xor(l, 1); l += __shfl_xor(l, 2);
      l += __shfl_xor(l, 4); l += __shfl_xor(l, 8);
      lrow[q] = lrow[q] * sf[q] + l;
#pragma unroll
      for (int n = 0; n < 4; ++n) oacc[n][q] *= sf[q];
    }
    asm volatile("s_waitcnt lgkmcnt(0)" ::: "memory");
    short8 pa0 = *(const short8*)&Ps[w][fr * ST + kg * 8];
    short8 pa1 = *(const short8*)&Ps[w][fr * ST + kg * 8 + 32];
#pragma unroll
    for (int n = 0; n < 4; ++n) {
      short8 vf0 = *(const short8*)&Vs[(n * 16 + fr) * ST + kg * 8];
      short8 vf1 = *(const short8*)&Vs[(n * 16 + fr) * ST + kg * 8 + 32];
      oacc[n] = __builtin_amdgcn_mfma_f32_16x16x32_bf16(pa0, vf0, oacc[n], 0, 0, 0);
      oacc[n] = __builtin_amdgcn_mfma_f32_16x16x32_bf16(pa1, vf1, oacc[n], 0, 0, 0);
    }
  }
  int orow = b * Wn + qt * 64 + w * 16 + kg * 4;
#pragma unroll
  for (int q = 0; q < 4; ++q) {
    float inv = 1.0f / lrow[q];
#pragma unroll
    for (int n = 0; n < 4; ++n)
      ao[(long)(orow + q) * Cd + h * 64 + n * 16 + fr] = f2bu(oacc[n][q] * inv);
  }
}

template <int BM, int BN, int EPI, int OUTBF>
static inline void mgemm(hipStream_t st,
    const u16* A, int lda, long sA1, long sA2,
    const u16* Bt, int ldb, long sB1, long sB2,
    void* C, int ldc, long sC1, long sC2,
    const float* R, int M, int N, int K, int nz, int zdiv,
    u16* D2 = nullptr, const float* PL = nullptr, const u16* VL = nullptr,
    const float* WP = nullptr) {
  dim3 g((N + BN - 1) / BN, (M + BM - 1) / BM, nz);
  hipLaunchKernelGGL((k_mgemm<BM, BN, EPI, OUTBF>), g, dim3(256), 0, st,
                     A, lda, sA1, sA2, Bt, ldb, sB1, sB2, C, ldc, sC1, sC2,
                     R ? R : (const float*)C, D2, PL, VL, WP, K, zdiv);
}

}  // namespace

extern "C" void kernel_launch(void* const* d_in, const int* in_sizes, int n_in,
                              void* d_out, int out_size, void* d_ws, size_t ws_size,
                              hipStream_t stream) {
  (void)in_sizes; (void)n_in; (void)out_size; (void)ws_size;
  const int*   x          = (const int*)d_in[0];
  const int*   amask      = (const int*)d_in[1];
  const float* cte        = (const float*)d_in[2];
  const float* cpe        = (const float*)d_in[3];
  const float* wpe        = (const float*)d_in[4];
  const float* ln1g       = (const float*)d_in[5];
  const float* ln1b       = (const float*)d_in[6];
  const float* ln2g       = (const float*)d_in[7];
  const float* ln2b       = (const float*)d_in[8];
  const float* ln3g       = (const float*)d_in[9];
  const float* ln3b       = (const float*)d_in[10];
  const float* cattn_w    = (const float*)d_in[11];
  const float* cattn_proj = (const float*)d_in[12];
  const float* wattn_w    = (const float*)d_in[13];
  const float* wattn_proj = (const float*)d_in[14];
  const float* mlp_fc     = (const float*)d_in[15];
  const float* mlp_proj   = (const float*)d_in[16];
  const float* proj_w     = (const float*)d_in[17];
  const float* lm_head    = (const float*)d_in[18];
  float* out = (float*)d_out;

  char* base = (char*)d_ws;
  size_t off = 0;
  auto alloc = [&](size_t bytes) -> char* {
    char* r = base + off;
    off += (bytes + 255) & ~(size_t)255;
    return r;
  };
  int*   lastix = (int*)alloc((size_t)BW * 4);
  float* plast  = (float*)alloc((size_t)BW * 8 * 4);
  u16*   ctx    = (u16*)alloc((size_t)NROW * Cd * 2);            // 100.7 MB
  char*  big    = alloc((size_t)105 * 1024 * 1024);              // aliased region
  u16*   kvq    = (u16*)alloc((size_t)BW * C3 * 2);              // qkvc / qkvw
  u16*   qin    = (u16*)alloc((size_t)BW * Cd * 2);
  float* state  = (float*)alloc((size_t)BW * Cd * 4);
  u16*   stateb = (u16*)alloc((size_t)BW * Cd * 2);
  u16*   hln    = (u16*)alloc((size_t)BW * Cd * 2);
  u16*   ao     = (u16*)alloc((size_t)BW * Cd * 2);
  u16*   wT     = (u16*)alloc((size_t)2 * (2 * C3 * Cd + 2 * Cd * Cd + 2 * FF * Cd) * 2);
  u16*   wcb    = (u16*)alloc((size_t)2 * Cd * C3 * 2);          // bf16 cattn_w (orig layout)
  u16*   projwb = (u16*)alloc((size_t)Cd * CB * Cd * 2);
  u16*   lmhT   = (u16*)alloc((size_t)Vn * Cd * 2);

  // aliased views inside big (lifetimes disjoint):
  u16*   U     = (u16*)big;                                     // char stage [BW,8,512]
  u16*   qtil  = (u16*)(big + (size_t)35651584);                // char stage [BW,8,512]
  u16*   mlph  = (u16*)big;                                     // mlp stage [BW,2048]
  u16*   combT = (u16*)big;                                     // final [6144,512]

  size_t lw = (size_t)(2 * C3 * Cd + 2 * Cd * Cd + 2 * FF * Cd);
  auto cwT    = [&](int l) { return wT + l * lw; };
  auto cprojT = [&](int l) { return wT + l * lw + C3 * Cd; };
  auto wwT    = [&](int l) { return wT + l * lw + C3 * Cd + Cd * Cd; };
  auto wprojT = [&](int l) { return wT + l * lw + 2 * C3 * Cd + Cd * Cd; };
  auto fcT    = [&](int l) { return wT + l * lw + 2 * C3 * Cd + 2 * Cd * Cd; };
  auto mprojT = [&](int l) { return wT + l * lw + 2 * C3 * Cd + 2 * Cd * Cd + FF * Cd; };

  // ---- prep (weights + lastix in one launch) ----
  hipLaunchKernelGGL(k_prep, dim3(5936), dim3(256), 0, stream,
                     proj_w, projwb, cattn_w, wcb, lm_head, lmhT,
                     cattn_proj, wattn_w, wattn_proj, mlp_fc, mlp_proj, wT,
                     amask, lastix);
  hipLaunchKernelGGL(k_embed_ln, dim3(NROW), dim3(64), 0, stream,
                     x, cte, cpe, ln1g, ln1b, lastix, ctx, qin);

  for (int l = 0; l < Lln; ++l) {
    u16* qkvc = kvq;   // char stage view
    u16* qkvw = kvq;   // word stage view (disjoint lifetime)
    if (l > 0)
      hipLaunchKernelGGL(k_ln, dim3(BW), dim3(64), 0, stream, state, qin, ln1g + Cd, ln1b + Cd);
    // last-row q|k|v: [BW,1536]
    mgemm<128, 64, 0, 1>(stream, qin, Cd, 0, 0, cwT(l), Cd, 0, 0,
                         qkvc, C3, 0, 0, nullptr, BW, C3, Cd, 1, 1);
    // qtil_h = q_h @ Wk_h^T  (batched z=head, K=64) -> [BW, 8, 512]
    mgemm<64, 64, 0, 1>(stream, qkvc, C3, 0, 64,
                        wcb + (size_t)l * Cd * C3 + Cd, C3, 0, 64,
                        qtil, 8 * Cd, 0, Cd, nullptr, BW, Cd, HDn, 8, 8);
    // fused scores(MFMA)/softmax/aggregate(MFMA)
    hipLaunchKernelGGL(k_cattn2, dim3(BW), dim3(256), 0, stream,
                       ctx, qtil, qkvc, lastix, U, plast);
    // O = U @ Wv_h + p_li*v_last (+wpe at l=0) -> ao bf16   [BN=32: 1024 blk]
    mgemm<64, 32, 4, 1>(stream, U, 8 * Cd, 0, Cd,
                        cwT(l) + (size_t)(2 * Cd) * Cd, Cd, 0, (long)HDn * Cd,
                        ao, Cd, 0, HDn, nullptr, BW, HDn, Cd, 8, 8,
                        nullptr, plast, qkvc, l == 0 ? wpe : nullptr);
    // state = attn_out @ cattn_proj (no residual), f32      [BN=32: 1024 blk]
    mgemm<64, 32, 0, 0>(stream, ao, Cd, 0, 0, cprojT(l), Cd, 0, 0,
                        state, Cd, 0, 0, nullptr, BW, Cd, Cd, 1, 1);
    // word attention (fused flash, V transposed in-kernel)
    hipLaunchKernelGGL(k_ln, dim3(BW), dim3(64), 0, stream, state, hln, ln2g + l * Cd, ln2b + l * Cd);
    mgemm<128, 64, 0, 1>(stream, hln, Cd, 0, 0, wwT(l), Cd, 0, 0,
                         qkvw, C3, 0, 0, nullptr, BW, C3, Cd, 1, 1);
    hipLaunchKernelGGL(k_fattn, dim3(8, 64), dim3(256), 0, stream, qkvw, ao);
    // state += wordo @ wattn_proj                            [BN=32: 1024 blk]
    mgemm<64, 32, 1, 0>(stream, ao, Cd, 0, 0, wprojT(l), Cd, 0, 0,
                        state, Cd, 0, 0, state, BW, Cd, Cd, 1, 1);
    // MLP
    hipLaunchKernelGGL(k_ln, dim3(BW), dim3(64), 0, stream, state, hln, ln3g + l * Cd, ln3b + l * Cd);
    mgemm<64, 64, 2, 1>(stream, hln, Cd, 0, 0, fcT(l), Cd, 0, 0,
                        mlph, FF, 0, 0, nullptr, BW, FF, Cd, 1, 1);
    // state += gelu_h @ mlp_proj (dual-store)                [BN=32: 1024 blk]
    mgemm<64, 32, 3, 0>(stream, mlph, FF, 0, 0, mprojT(l), FF, 0, 0,
                        state, Cd, 0, 0, state, BW, Cd, FF, 1, 1, stateb);
  }

  // combT[j*256+v, k] = sum_c lm_head[c,v] proj_w[k, j*512+c]
  mgemm<64, 64, 0, 1>(stream, lmhT, Cd, 0, 0,
                      projwb, CB * Cd, 0, Cd,
                      combT, Cd, 0, (long)Vn * Cd,
                      nullptr, Vn, Cd, Cd, CB, CB);
  // logits = stateb @ combT^T -> out f32 [BW, CBLK*VOCAB]
  mgemm<128, 128, 0, 0>(stream, stateb, Cd, 0, 0, combT, Cd, 0, 0,
                        out, CB * Vn, 0, 0, nullptr, BW, CB * Vn, Cd, 1, 1);
}

// Round 16
// 527.342 us; speedup vs baseline: 1.0231x; 1.0231x over previous
//
#include <hip/hip_runtime.h>
#include <hip/hip_bf16.h>
#include <math.h>

// GPT_86715389706669 — hierarchical char/word transformer forward.
// Round 16: revert to R14 exactly (528us best). R15's BN=32 tile regressed
// (539us): shrinking BN doubles B refetch + idles half the stage threads —
// the occupancy lever only pays when block count grows without per-block
// overhead. R14 = MFMA scores+aggregate cattn, fused flash word attn,
// consolidated prep, launch-minimized chain.

namespace {

constexpr int Bn = 8, Wn = 512, CB = 24, Cd = 512, Hn = 8, Lln = 2, Vn = 256, HDn = 64;
constexpr int BW = Bn * Wn;       // 4096
constexpr int C3 = 3 * Cd;        // 1536
constexpr int FF = 4 * Cd;        // 2048
constexpr int NROW = BW * CB;     // 98304 char rows (strided layout)

typedef unsigned short u16;
typedef short short8 __attribute__((ext_vector_type(8)));
typedef float f32x4 __attribute__((ext_vector_type(4)));
typedef __attribute__((address_space(1))) void gvoid_t;
typedef __attribute__((address_space(3))) void lvoid_t;

__device__ __forceinline__ u16 f2bu(float f) {
  __hip_bfloat16 h = __float2bfloat16(f);   // RTNE
  return __builtin_bit_cast(u16, h);
}
__device__ __forceinline__ float bu2f(u16 u) {
  return __bfloat162float(__builtin_bit_cast(__hip_bfloat16, u));
}
__device__ __forceinline__ float geluf(float x) {
  return 0.5f * x * (1.0f + erff(x * 0.7071067811865475f));
}
__device__ __forceinline__ void gl16(const void* g, void* l) {
  __builtin_amdgcn_global_load_lds((gvoid_t*)g, (lvoid_t*)l, 16, 0, 0);
}

// ---------------- consolidated weight prep (+ lastix) ----------------
__device__ __forceinline__ void f2b8(const float* __restrict__ s, u16* __restrict__ d) {
  float4 a = *(const float4*)s;
  float4 b = *(const float4*)(s + 4);
  union { uint4 u; u16 h[8]; } pk;
  pk.h[0] = f2bu(a.x); pk.h[1] = f2bu(a.y); pk.h[2] = f2bu(a.z); pk.h[3] = f2bu(a.w);
  pk.h[4] = f2bu(b.x); pk.h[5] = f2bu(b.y); pk.h[6] = f2bu(b.z); pk.h[7] = f2bu(b.w);
  *(uint4*)d = pk.u;
}

__device__ __forceinline__ void wT_tile(const float* __restrict__ src, u16* __restrict__ dst,
                                        int K, int N, int n0, int k0,
                                        u16 T[64][72], int tid) {
  int kl = tid >> 2, nc = (tid & 3) * 16;
  const float* s = src + (long)(k0 + kl) * N + n0 + nc;
#pragma unroll
  for (int u = 0; u < 4; ++u) {
    float4 f = *(const float4*)(s + u * 4);
    T[nc + u * 4 + 0][kl] = f2bu(f.x);
    T[nc + u * 4 + 1][kl] = f2bu(f.y);
    T[nc + u * 4 + 2][kl] = f2bu(f.z);
    T[nc + u * 4 + 3][kl] = f2bu(f.w);
  }
  __syncthreads();
  int nl = tid >> 2, kc = (tid & 3) * 16;
  u16* d = dst + (long)(n0 + nl) * K + k0 + kc;
  *(uint4*)d = *(uint4*)&T[nl][kc];
  *(uint4*)(d + 8) = *(uint4*)&T[nl][kc + 8];
}

// grid = 3072 (projwb) + 768 (wcb) + 32 (lmhT) + 2048 (wT) + 16 (lastix) = 5936
__global__ __launch_bounds__(256) void k_prep(
    const float* __restrict__ proj_w, u16* __restrict__ projwb,
    const float* __restrict__ cattn_w, u16* __restrict__ wcb,
    const float* __restrict__ lm_head, u16* __restrict__ lmhT,
    const float* __restrict__ cattn_proj, const float* __restrict__ wattn_w,
    const float* __restrict__ wattn_proj, const float* __restrict__ mlp_fc,
    const float* __restrict__ mlp_proj, u16* __restrict__ wT,
    const int* __restrict__ amask, int* __restrict__ lastix) {
  __shared__ u16 T[64][72];
  int b = blockIdx.x, tid = threadIdx.x;
  if (b >= 5920) {
    int i = (b - 5920) * 256 + tid;
    if (i < BW) {
      int s = 0;
#pragma unroll
      for (int j = 0; j < CB; ++j) s += amask[i * CB + j];
      lastix[i] = s - 1;
    }
    return;
  }
  if (b < 3072) { long i = ((long)b * 256 + tid) * 8; f2b8(proj_w + i, projwb + i); return; }
  b -= 3072;
  if (b < 768) { long i = ((long)b * 256 + tid) * 8; f2b8(cattn_w + i, wcb + i); return; }
  b -= 768;
  if (b < 32) { wT_tile(lm_head, lmhT, Cd, Vn, (b & 3) * 64, (b >> 2) * 64, T, tid); return; }
  b -= 32;
  int l = b >> 10, r = b & 1023;
  size_t lw = (size_t)(2 * C3 * Cd + 2 * Cd * Cd + 2 * FF * Cd);
  u16* bl = wT + l * lw;
  const float* src; u16* dst; int K, N, nt;
  if (r < 192)      { src = cattn_w + (size_t)l * Cd * C3;    dst = bl;                              K = Cd; N = C3; nt = 24; }
  else if (r < 256) { src = cattn_proj + (size_t)l * Cd * Cd; dst = bl + C3 * Cd;                    K = Cd; N = Cd; nt = 8;  r -= 192; }
  else if (r < 448) { src = wattn_w + (size_t)l * Cd * C3;    dst = bl + C3 * Cd + Cd * Cd;          K = Cd; N = C3; nt = 24; r -= 256; }
  else if (r < 512) { src = wattn_proj + (size_t)l * Cd * Cd; dst = bl + 2 * C3 * Cd + Cd * Cd;      K = Cd; N = Cd; nt = 8;  r -= 448; }
  else if (r < 768) { src = mlp_fc + (size_t)l * Cd * FF;     dst = bl + 2 * C3 * Cd + 2 * Cd * Cd;  K = Cd; N = FF; nt = 32; r -= 512; }
  else              { src = mlp_proj + (size_t)l * FF * Cd;   dst = bl + 2 * C3 * Cd + 2 * Cd * Cd + FF * Cd; K = FF; N = Cd; nt = 8; r -= 768; }
  wT_tile(src, dst, K, N, (r % nt) * 64, (r / nt) * 64, T, tid);
}

// ---------------- fused embed + LN -> ctx (+ last row to qin) ----------------
__global__ __launch_bounds__(64) void k_embed_ln(
    const int* __restrict__ x, const float* __restrict__ cte, const float* __restrict__ cpe,
    const float* __restrict__ g, const float* __restrict__ b,
    const int* __restrict__ lastix, u16* __restrict__ ctx, u16* __restrict__ qin) {
  int r = blockIdx.x;
  int bw = r / CB, ch = r - bw * CB;
  int li = lastix[bw];
  if (ch > li) return;
  int tok = x[r];
  const float* e = cte + (long)tok * Cd;
  const float* pe = cpe + (long)ch * Cd;
  int lane = threadIdx.x;
  float v[8];
  float s = 0.f, sq = 0.f;
#pragma unroll
  for (int u = 0; u < 2; ++u) {
    float4 a = *(const float4*)(e + u * 256 + lane * 4);
    float4 p4 = *(const float4*)(pe + u * 256 + lane * 4);
    v[u * 4 + 0] = a.x + p4.x; v[u * 4 + 1] = a.y + p4.y;
    v[u * 4 + 2] = a.z + p4.z; v[u * 4 + 3] = a.w + p4.w;
  }
#pragma unroll
  for (int u = 0; u < 8; ++u) { s += v[u]; sq += v[u] * v[u]; }
#pragma unroll
  for (int m = 32; m; m >>= 1) { s += __shfl_xor(s, m); sq += __shfl_xor(sq, m); }
  float mean = s * (1.0f / Cd);
  float var = sq * (1.0f / Cd) - mean * mean;
  float rs = rsqrtf(var + 1e-5f);
  u16* o = ctx + (long)r * Cd;
  u16* oq = qin + (long)bw * Cd;
  int isLast = (ch == li);
#pragma unroll
  for (int u = 0; u < 2; ++u) {
    int c0 = u * 256 + lane * 4;
    float4 g4 = *(const float4*)(g + c0);
    float4 b4 = *(const float4*)(b + c0);
    float o0 = (v[u * 4 + 0] - mean) * rs * g4.x + b4.x;
    float o1 = (v[u * 4 + 1] - mean) * rs * g4.y + b4.y;
    float o2 = (v[u * 4 + 2] - mean) * rs * g4.z + b4.z;
    float o3 = (v[u * 4 + 3] - mean) * rs * g4.w + b4.w;
    uint2 w;
    w.x = (unsigned)f2bu(o0) | ((unsigned)f2bu(o1) << 16);
    w.y = (unsigned)f2bu(o2) | ((unsigned)f2bu(o3) << 16);
    *(uint2*)(o + c0) = w;
    if (isLast) *(uint2*)(oq + c0) = w;
  }
}

// ---------------- LayerNorm rows [BW, C], f32 in -> bf16 out ----------------
__global__ __launch_bounds__(64) void k_ln(
    const float* __restrict__ X, u16* __restrict__ Y,
    const float* __restrict__ g, const float* __restrict__ b) {
  long r = blockIdx.x;
  const float* xr = X + r * Cd;
  int lane = threadIdx.x;
  float v[8];
  float s = 0.f, sq = 0.f;
#pragma unroll
  for (int u = 0; u < 2; ++u) {
    float4 a = *(const float4*)(xr + u * 256 + lane * 4);
    v[u * 4 + 0] = a.x; v[u * 4 + 1] = a.y; v[u * 4 + 2] = a.z; v[u * 4 + 3] = a.w;
  }
#pragma unroll
  for (int u = 0; u < 8; ++u) { s += v[u]; sq += v[u] * v[u]; }
#pragma unroll
  for (int m = 32; m; m >>= 1) { s += __shfl_xor(s, m); sq += __shfl_xor(sq, m); }
  float mean = s * (1.0f / Cd);
  float var = sq * (1.0f / Cd) - mean * mean;
  float rs = rsqrtf(var + 1e-5f);
  u16* o = Y + r * Cd;
#pragma unroll
  for (int u = 0; u < 2; ++u) {
    int c0 = u * 256 + lane * 4;
    float4 g4 = *(const float4*)(g + c0);
    float4 b4 = *(const float4*)(b + c0);
    float o0 = (v[u * 4 + 0] - mean) * rs * g4.x + b4.x;
    float o1 = (v[u * 4 + 1] - mean) * rs * g4.y + b4.y;
    float o2 = (v[u * 4 + 2] - mean) * rs * g4.z + b4.z;
    float o3 = (v[u * 4 + 3] - mean) * rs * g4.w + b4.w;
    uint2 w;
    w.x = (unsigned)f2bu(o0) | ((unsigned)f2bu(o1) << 16);
    w.y = (unsigned)f2bu(o2) | ((unsigned)f2bu(o3) << 16);
    *(uint2*)(o + c0) = w;
  }
}

// ---------------- bf16 MFMA GEMM: D = A @ Bt^T ----------------
// EPI: 0=store, 1=acc+R, 2=gelu, 3=acc+R dual-store (f32 Cv + bf16 D2),
//      4=acc + PL[gr*8+z2]*VL[gr,2C+z2*64+gc] (+WP)  [char-attn O assembly]
template <int BM, int BN, int EPI, int OUTBF>
__global__ __launch_bounds__(256) void k_mgemm(
    const u16* __restrict__ A, int lda, long sA1, long sA2,
    const u16* __restrict__ Bt, int ldb, long sB1, long sB2,
    void* __restrict__ Cv, int ldc, long sC1, long sC2,
    const float* __restrict__ R, u16* __restrict__ D2,
    const float* __restrict__ PL, const u16* __restrict__ VL,
    const float* __restrict__ WP, int K, int zdiv) {
  constexpr int WM = BM / 2;
  constexpr int WN = BN / 2;
  constexpr int FM = WM / 16, FN = WN / 16;
  __shared__ u16 As[BM * 32];
  __shared__ u16 Bs[BN * 32];
  long m0 = (long)blockIdx.y * BM, n0 = (long)blockIdx.x * BN;
  int z = blockIdx.z;
  int z1 = z / zdiv, z2 = z - z1 * zdiv;
  A += z1 * sA1 + z2 * sA2;
  Bt += z1 * sB1 + z2 * sB2;
  long coff = z1 * sC1 + z2 * sC2;
  int tid = threadIdx.x;
  int wid = tid >> 6, lane = tid & 63;
  int wr = wid >> 1, wc = wid & 1;

  const int srow = tid >> 2, skk = (tid & 3) * 8;
  const u16* Ald[BM / 64];
  const u16* Bld[BN / 64];
#pragma unroll
  for (int i = 0; i < BM / 64; ++i) Ald[i] = A + (m0 + srow + i * 64) * (long)lda + skk;
#pragma unroll
  for (int i = 0; i < BN / 64; ++i) Bld[i] = Bt + (n0 + srow + i * 64) * (long)ldb + skk;

  f32x4 acc[FM][FN] = {};
  const int fr = lane & 15, kg = lane >> 4;

  for (int k0 = 0; k0 < K; k0 += 32) {
#pragma unroll
    for (int i = 0; i < BM / 64; ++i) gl16(Ald[i] + k0, &As[(tid + i * 256) * 8]);
#pragma unroll
    for (int i = 0; i < BN / 64; ++i) gl16(Bld[i] + k0, &Bs[(tid + i * 256) * 8]);
    __syncthreads();
    short8 af[FM], bf[FN];
#pragma unroll
    for (int m = 0; m < FM; ++m)
      af[m] = *(const short8*)&As[(wr * WM + m * 16 + fr) * 32 + kg * 8];
#pragma unroll
    for (int n = 0; n < FN; ++n)
      bf[n] = *(const short8*)&Bs[(wc * WN + n * 16 + fr) * 32 + kg * 8];
#pragma unroll
    for (int m = 0; m < FM; ++m)
#pragma unroll
      for (int n = 0; n < FN; ++n)
        acc[m][n] = __builtin_amdgcn_mfma_f32_16x16x32_bf16(af[m], bf[n], acc[m][n], 0, 0, 0);
    __syncthreads();
  }
  // C/D layout: col = lane&15, row = (lane>>4)*4 + q
  int ccol = lane & 15, crow4 = (lane >> 4) * 4;
#pragma unroll
  for (int m = 0; m < FM; ++m)
#pragma unroll
    for (int n = 0; n < FN; ++n)
#pragma unroll
      for (int q = 0; q < 4; ++q) {
        long gr = m0 + wr * WM + m * 16 + crow4 + q;
        long gc = n0 + wc * WN + n * 16 + ccol;
        float v = acc[m][n][q];
        long idx = gr * (long)ldc + gc + coff;
        if (EPI == 1 || EPI == 3) v += R[idx];
        if (EPI == 2) v = geluf(v);
        if (EPI == 4) {
          v += PL[gr * 8 + z2] * bu2f(VL[gr * (long)C3 + 2 * Cd + z2 * 64 + gc]);
          if (WP) v += WP[(long)(gr & (Wn - 1)) * Cd + z2 * 64 + gc];
        }
        if (EPI == 3) {
          ((float*)Cv)[idx] = v;
          D2[idx] = f2bu(v);
        } else if (OUTBF) {
          ((u16*)Cv)[idx] = f2bu(v);
        } else {
          ((float*)Cv)[idx] = v;
        }
      }
}

// ---------------- fused char attention: MFMA scores + MFMA aggregate ----------------
__global__ __launch_bounds__(256) void k_cattn2(
    const u16* __restrict__ ctx, const u16* __restrict__ qtil,
    const u16* __restrict__ qkvc, const int* __restrict__ lastix,
    u16* __restrict__ U, float* __restrict__ plast) {
  constexpr int CS = 520;                  // padded row stride (u16)
  int gw = blockIdx.x;
  int li = lastix[gw];
  __shared__ u16 ctxs[CB - 1][CS];         // rows 0..22 (j = li from qkvc)
  __shared__ float spf[4][Hn][32];         // per-wave score partials
  __shared__ float sp[Hn][CB];
  __shared__ u16 Pb[16][40];               // bf16 P, zero-padded
  int tid = threadIdx.x;
  for (int u = tid; u < li * 64; u += 256) {
    int row = u >> 6, c = (u & 63) * 8;
    *(uint4*)&ctxs[row][c] = *(const uint4*)(ctx + ((long)(gw * CB + row)) * Cd + c);
  }
  for (int u = tid; u < (CB - 1 - li) * 64; u += 256) {   // zero unloaded rows
    int row = li + (u >> 6), c = (u & 63) * 8;
    *(uint4*)&ctxs[row][c] = make_uint4(0, 0, 0, 0);
  }
  __syncthreads();
  int w = tid >> 6, lane = tid & 63;
  int fr = lane & 15, kg = lane >> 4;
  {
    const u16* qbase = qtil + (long)gw * 4096 + (fr & 7) * 512 + w * 128 + kg * 8;
    int r0 = fr;
    int r1 = 16 + fr; if (r1 > CB - 2) r1 = CB - 2;
    f32x4 acc0 = {}, acc1 = {};
#pragma unroll
    for (int kk = 0; kk < 4; ++kk) {
      short8 af = *(const short8*)(qbase + kk * 32);
      short8 b0 = *(const short8*)&ctxs[r0][w * 128 + kk * 32 + kg * 8];
      short8 b1 = *(const short8*)&ctxs[r1][w * 128 + kk * 32 + kg * 8];
      acc0 = __builtin_amdgcn_mfma_f32_16x16x32_bf16(af, b0, acc0, 0, 0, 0);
      acc1 = __builtin_amdgcn_mfma_f32_16x16x32_bf16(af, b1, acc1, 0, 0, 0);
    }
    if (lane < 32) {
      int jj = lane & 15;
#pragma unroll
      for (int q = 0; q < 4; ++q) {
        int h = (lane >> 4) * 4 + q;
        spf[w][h][jj] = acc0[q];
        spf[w][h][16 + jj] = acc1[q];
      }
    }
  }
  __syncthreads();
  {
    int h = tid >> 5, j = tid & 31;
    if (j < CB)
      sp[h][j] = (spf[0][h][j] + spf[1][h][j] + spf[2][h][j] + spf[3][h][j]) * 0.125f;
  }
  for (int u = tid; u < 16 * 40; u += 256) ((u16*)Pb)[u] = 0;
  __syncthreads();
  if (tid < 8) {   // s_{h,li} = q_h . k_h (last row)
    const u16* qq = qkvc + (long)gw * C3 + tid * 64;
    const u16* kk = qq + Cd;
    float s = 0.f;
#pragma unroll
    for (int u = 0; u < 64; ++u) s += bu2f(qq[u]) * bu2f(kk[u]);
    sp[tid][li] = s * 0.125f;
  }
  __syncthreads();
  if (tid < 8) {
    float m = -3.4e38f;
    for (int jj = 0; jj <= li; ++jj) m = fmaxf(m, sp[tid][jj]);
    float s = 0.f;
    for (int jj = 0; jj <= li; ++jj) { float e = expf(sp[tid][jj] - m); sp[tid][jj] = e; s += e; }
    float inv = 1.0f / s;
    for (int jj = 0; jj < li; ++jj) Pb[tid][jj] = f2bu(sp[tid][jj] * inv);
    plast[gw * 8 + tid] = sp[tid][li] * inv;
  }
  __syncthreads();
  // aggregate: per wave 8 n-tiles of 16 d-cols; K = 32 (j, zero-padded)
  {
    short8 pf = *(const short8*)&Pb[fr][kg * 8];
    u16* ub = U + (long)gw * 4096;
#pragma unroll
    for (int t = 0; t < 8; ++t) {
      int n0 = (w * 8 + t) * 16;
      union { short8 v; u16 e[8]; } bf;
#pragma unroll
      for (int u = 0; u < 8; ++u) {
        int k = kg * 8 + u;
        int kc = k < CB - 1 ? k : CB - 2;   // clamp; rows >= li are zero
        bf.e[u] = ctxs[kc][n0 + fr];
      }
      f32x4 a = {};
      a = __builtin_amdgcn_mfma_f32_16x16x32_bf16(pf, bf.v, a, 0, 0, 0);
      if (kg < 2) {
#pragma unroll
        for (int q = 0; q < 4; ++q)
          ub[(kg * 4 + q) * 512 + n0 + fr] = f2bu(a[q]);
      }
    }
  }
}

// ---------------- fused flash word attention (V transposed in-LDS from qkv) ----------------
__global__ __launch_bounds__(256) void k_fattn(
    const u16* __restrict__ qkv, u16* __restrict__ ao) {
  constexpr int ST = 68;                 // LDS row stride (u16)
  __shared__ u16 Ks[64 * ST];
  __shared__ u16 Vs[64 * ST];            // Vs[d][j] (transposed at staging)
  __shared__ u16 Ps[4][16 * ST];
  int qt = blockIdx.x;
  int z  = blockIdx.y;
  int b = z >> 3, h = z & 7;
  int tid = threadIdx.x;
  int w = tid >> 6, lane = tid & 63;
  int fr = lane & 15, kg = lane >> 4;

  short8 qf[2];
  {
    const u16* qp = qkv + ((long)(b * Wn + qt * 64 + w * 16 + fr)) * C3 + h * 64 + kg * 8;
    qf[0] = *(const short8*)qp;
    qf[1] = *(const short8*)(qp + 32);
  }
  f32x4 oacc[4] = {};
  float mrow[4], lrow[4];
#pragma unroll
  for (int q = 0; q < 4; ++q) { mrow[q] = -3.4e38f; lrow[q] = 0.f; }

  for (int kt = 0; kt <= qt; ++kt) {
    __syncthreads();
    {
      int r = tid >> 2, c = (tid & 3) * 16;
      const u16* kp = qkv + ((long)(b * Wn + kt * 64 + r)) * C3 + Cd + h * 64 + c;
      *(uint4*)&Ks[r * ST + c] = *(const uint4*)kp;
      *(uint4*)&Ks[r * ST + c + 8] = *(const uint4*)(kp + 8);
      const u16* vp = kp + Cd;             // qkv V section, same row/cols
      uint4 v0 = *(const uint4*)vp;
      uint4 v1 = *(const uint4*)(vp + 8);
      const u16* e0 = (const u16*)&v0;
      const u16* e1 = (const u16*)&v1;
#pragma unroll
      for (int u = 0; u < 8; ++u) Vs[(c + u) * ST + r] = e0[u];
#pragma unroll
      for (int u = 0; u < 8; ++u) Vs[(c + 8 + u) * ST + r] = e1[u];
    }
    __syncthreads();
    f32x4 s[4];
#pragma unroll
    for (int n = 0; n < 4; ++n) {
      short8 kf0 = *(const short8*)&Ks[(n * 16 + fr) * ST + kg * 8];
      short8 kf1 = *(const short8*)&Ks[(n * 16 + fr) * ST + kg * 8 + 32];
      f32x4 a = {};
      a = __builtin_amdgcn_mfma_f32_16x16x32_bf16(qf[0], kf0, a, 0, 0, 0);
      a = __builtin_amdgcn_mfma_f32_16x16x32_bf16(qf[1], kf1, a, 0, 0, 0);
      s[n] = a;
    }
    int irow0 = qt * 64 + w * 16 + kg * 4;
#pragma unroll
    for (int n = 0; n < 4; ++n) {
      int jcol = kt * 64 + n * 16 + fr;
#pragma unroll
      for (int q = 0; q < 4; ++q) {
        float v = s[n][q] * 0.125f;
        s[n][q] = (jcol > irow0 + q) ? -3.4e38f : v;
      }
    }
    float sf[4];
#pragma unroll
    for (int q = 0; q < 4; ++q) {
      float mm = fmaxf(fmaxf(s[0][q], s[1][q]), fmaxf(s[2][q], s[3][q]));
      mm = fmaxf(mm, __shfl_xor(mm, 1));
      mm = fmaxf(mm, __shfl_xor(mm, 2));
      mm = fmaxf(mm, __shfl_xor(mm, 4));
      mm = fmaxf(mm, __shfl_xor(mm, 8));
      float mnew = fmaxf(mrow[q], mm);
      sf[q] = expf(mrow[q] - mnew);
      mrow[q] = mnew;
    }
    float ls[4] = {0.f, 0.f, 0.f, 0.f};
#pragma unroll
    for (int n = 0; n < 4; ++n) {
#pragma unroll
      for (int q = 0; q < 4; ++q) {
        float p = expf(s[n][q] - mrow[q]);
        u16 pb = f2bu(p);
        ls[q] += bu2f(pb);
        Ps[w][(kg * 4 + q) * ST + n * 16 + fr] = pb;
      }
    }
#pragma unroll
    for (int q = 0; q < 4; ++q) {
      float l = ls[q];
      l += __shfl_xor(l, 1); l += __shfl_xor(l, 2);
      l += __shfl_xor(l, 4); l += __shfl_xor(l, 8);
      lrow[q] = lrow[q] * sf[q] + l;
#pragma unroll
      for (int n = 0; n < 4; ++n) oacc[n][q] *= sf[q];
    }
    asm volatile("s_waitcnt lgkmcnt(0)" ::: "memory");
    short8 pa0 = *(const short8*)&Ps[w][fr * ST + kg * 8];
    short8 pa1 = *(const short8*)&Ps[w][fr * ST + kg * 8 + 32];
#pragma unroll
    for (int n = 0; n < 4; ++n) {
      short8 vf0 = *(const short8*)&Vs[(n * 16 + fr) * ST + kg * 8];
      short8 vf1 = *(const short8*)&Vs[(n * 16 + fr) * ST + kg * 8 + 32];
      oacc[n] = __builtin_amdgcn_mfma_f32_16x16x32_bf16(pa0, vf0, oacc[n], 0, 0, 0);
      oacc[n] = __builtin_amdgcn_mfma_f32_16x16x32_bf16(pa1, vf1, oacc[n], 0, 0, 0);
    }
  }
  int orow = b * Wn + qt * 64 + w * 16 + kg * 4;
#pragma unroll
  for (int q = 0; q < 4; ++q) {
    float inv = 1.0f / lrow[q];
#pragma unroll
    for (int n = 0; n < 4; ++n)
      ao[(long)(orow + q) * Cd + h * 64 + n * 16 + fr] = f2bu(oacc[n][q] * inv);
  }
}

template <int BM, int BN, int EPI, int OUTBF>
static inline void mgemm(hipStream_t st,
    const u16* A, int lda, long sA1, long sA2,
    const u16* Bt, int ldb, long sB1, long sB2,
    void* C, int ldc, long sC1, long sC2,
    const float* R, int M, int N, int K, int nz, int zdiv,
    u16* D2 = nullptr, const float* PL = nullptr, const u16* VL = nullptr,
    const float* WP = nullptr) {
  dim3 g(N / BN, (M + BM - 1) / BM, nz);
  hipLaunchKernelGGL((k_mgemm<BM, BN, EPI, OUTBF>), g, dim3(256), 0, st,
                     A, lda, sA1, sA2, Bt, ldb, sB1, sB2, C, ldc, sC1, sC2,
                     R ? R : (const float*)C, D2, PL, VL, WP, K, zdiv);
}

}  // namespace

extern "C" void kernel_launch(void* const* d_in, const int* in_sizes, int n_in,
                              void* d_out, int out_size, void* d_ws, size_t ws_size,
                              hipStream_t stream) {
  (void)in_sizes; (void)n_in; (void)out_size; (void)ws_size;
  const int*   x          = (const int*)d_in[0];
  const int*   amask      = (const int*)d_in[1];
  const float* cte        = (const float*)d_in[2];
  const float* cpe        = (const float*)d_in[3];
  const float* wpe        = (const float*)d_in[4];
  const float* ln1g       = (const float*)d_in[5];
  const float* ln1b       = (const float*)d_in[6];
  const float* ln2g       = (const float*)d_in[7];
  const float* ln2b       = (const float*)d_in[8];
  const float* ln3g       = (const float*)d_in[9];
  const float* ln3b       = (const float*)d_in[10];
  const float* cattn_w    = (const float*)d_in[11];
  const float* cattn_proj = (const float*)d_in[12];
  const float* wattn_w    = (const float*)d_in[13];
  const float* wattn_proj = (const float*)d_in[14];
  const float* mlp_fc     = (const float*)d_in[15];
  const float* mlp_proj   = (const float*)d_in[16];
  const float* proj_w     = (const float*)d_in[17];
  const float* lm_head    = (const float*)d_in[18];
  float* out = (float*)d_out;

  char* base = (char*)d_ws;
  size_t off = 0;
  auto alloc = [&](size_t bytes) -> char* {
    char* r = base + off;
    off += (bytes + 255) & ~(size_t)255;
    return r;
  };
  int*   lastix = (int*)alloc((size_t)BW * 4);
  float* plast  = (float*)alloc((size_t)BW * 8 * 4);
  u16*   ctx    = (u16*)alloc((size_t)NROW * Cd * 2);            // 100.7 MB
  char*  big    = alloc((size_t)105 * 1024 * 1024);              // aliased region
  u16*   kvq    = (u16*)alloc((size_t)BW * C3 * 2);              // qkvc / qkvw
  u16*   qin    = (u16*)alloc((size_t)BW * Cd * 2);
  float* state  = (float*)alloc((size_t)BW * Cd * 4);
  u16*   stateb = (u16*)alloc((size_t)BW * Cd * 2);
  u16*   hln    = (u16*)alloc((size_t)BW * Cd * 2);
  u16*   ao     = (u16*)alloc((size_t)BW * Cd * 2);
  u16*   wT     = (u16*)alloc((size_t)2 * (2 * C3 * Cd + 2 * Cd * Cd + 2 * FF * Cd) * 2);
  u16*   wcb    = (u16*)alloc((size_t)2 * Cd * C3 * 2);          // bf16 cattn_w (orig layout)
  u16*   projwb = (u16*)alloc((size_t)Cd * CB * Cd * 2);
  u16*   lmhT   = (u16*)alloc((size_t)Vn * Cd * 2);

  // aliased views inside big (lifetimes disjoint):
  u16*   U     = (u16*)big;                                     // char stage [BW,8,512]
  u16*   qtil  = (u16*)(big + (size_t)35651584);                // char stage [BW,8,512]
  u16*   mlph  = (u16*)big;                                     // mlp stage [BW,2048]
  u16*   combT = (u16*)big;                                     // final [6144,512]

  size_t lw = (size_t)(2 * C3 * Cd + 2 * Cd * Cd + 2 * FF * Cd);
  auto cwT    = [&](int l) { return wT + l * lw; };
  auto cprojT = [&](int l) { return wT + l * lw + C3 * Cd; };
  auto wwT    = [&](int l) { return wT + l * lw + C3 * Cd + Cd * Cd; };
  auto wprojT = [&](int l) { return wT + l * lw + 2 * C3 * Cd + Cd * Cd; };
  auto fcT    = [&](int l) { return wT + l * lw + 2 * C3 * Cd + 2 * Cd * Cd; };
  auto mprojT = [&](int l) { return wT + l * lw + 2 * C3 * Cd + 2 * Cd * Cd + FF * Cd; };

  // ---- prep (weights + lastix in one launch) ----
  hipLaunchKernelGGL(k_prep, dim3(5936), dim3(256), 0, stream,
                     proj_w, projwb, cattn_w, wcb, lm_head, lmhT,
                     cattn_proj, wattn_w, wattn_proj, mlp_fc, mlp_proj, wT,
                     amask, lastix);
  hipLaunchKernelGGL(k_embed_ln, dim3(NROW), dim3(64), 0, stream,
                     x, cte, cpe, ln1g, ln1b, lastix, ctx, qin);

  for (int l = 0; l < Lln; ++l) {
    u16* qkvc = kvq;   // char stage view
    u16* qkvw = kvq;   // word stage view (disjoint lifetime)
    if (l > 0)
      hipLaunchKernelGGL(k_ln, dim3(BW), dim3(64), 0, stream, state, qin, ln1g + Cd, ln1b + Cd);
    // last-row q|k|v: [BW,1536]
    mgemm<128, 64, 0, 1>(stream, qin, Cd, 0, 0, cwT(l), Cd, 0, 0,
                         qkvc, C3, 0, 0, nullptr, BW, C3, Cd, 1, 1);
    // qtil_h = q_h @ Wk_h^T  (batched z=head, K=64) -> [BW, 8, 512]
    mgemm<64, 64, 0, 1>(stream, qkvc, C3, 0, 64,
                        wcb + (size_t)l * Cd * C3 + Cd, C3, 0, 64,
                        qtil, 8 * Cd, 0, Cd, nullptr, BW, Cd, HDn, 8, 8);
    // fused scores(MFMA)/softmax/aggregate(MFMA)
    hipLaunchKernelGGL(k_cattn2, dim3(BW), dim3(256), 0, stream,
                       ctx, qtil, qkvc, lastix, U, plast);
    // O = U @ Wv_h + p_li*v_last (+wpe at l=0) -> ao bf16
    mgemm<64, 64, 4, 1>(stream, U, 8 * Cd, 0, Cd,
                        cwT(l) + (size_t)(2 * Cd) * Cd, Cd, 0, (long)HDn * Cd,
                        ao, Cd, 0, HDn, nullptr, BW, HDn, Cd, 8, 8,
                        nullptr, plast, qkvc, l == 0 ? wpe : nullptr);
    // state = attn_out @ cattn_proj (no residual), f32
    mgemm<64, 64, 0, 0>(stream, ao, Cd, 0, 0, cprojT(l), Cd, 0, 0,
                        state, Cd, 0, 0, nullptr, BW, Cd, Cd, 1, 1);
    // word attention (fused flash, V transposed in-kernel)
    hipLaunchKernelGGL(k_ln, dim3(BW), dim3(64), 0, stream, state, hln, ln2g + l * Cd, ln2b + l * Cd);
    mgemm<128, 64, 0, 1>(stream, hln, Cd, 0, 0, wwT(l), Cd, 0, 0,
                         qkvw, C3, 0, 0, nullptr, BW, C3, Cd, 1, 1);
    hipLaunchKernelGGL(k_fattn, dim3(8, 64), dim3(256), 0, stream, qkvw, ao);
    mgemm<64, 64, 1, 0>(stream, ao, Cd, 0, 0, wprojT(l), Cd, 0, 0,
                        state, Cd, 0, 0, state, BW, Cd, Cd, 1, 1);
    // MLP
    hipLaunchKernelGGL(k_ln, dim3(BW), dim3(64), 0, stream, state, hln, ln3g + l * Cd, ln3b + l * Cd);
    mgemm<64, 64, 2, 1>(stream, hln, Cd, 0, 0, fcT(l), Cd, 0, 0,
                        mlph, FF, 0, 0, nullptr, BW, FF, Cd, 1, 1);
    mgemm<64, 64, 3, 0>(stream, mlph, FF, 0, 0, mprojT(l), FF, 0, 0,
                        state, Cd, 0, 0, state, BW, Cd, FF, 1, 1, stateb);
  }

  // combT[j*256+v, k] = sum_c lm_head[c,v] proj_w[k, j*512+c]
  mgemm<64, 64, 0, 1>(stream, lmhT, Cd, 0, 0,
                      projwb, CB * Cd, 0, Cd,
                      combT, Cd, 0, (long)Vn * Cd,
                      nullptr, Vn, Cd, Cd, CB, CB);
  // logits = stateb @ combT^T -> out f32 [BW, CBLK*VOCAB]
  mgemm<128, 128, 0, 0>(stream, stateb, Cd, 0, 0, combT, Cd, 0, 0,
                        out, CB * Vn, 0, 0, nullptr, BW, CB * Vn, Cd, 1, 1);
}